// Round 1
// baseline (762.348 us; speedup 1.0000x reference)
//
#include <hip/hip_runtime.h>
#include <hip/hip_bf16.h>

typedef __attribute__((ext_vector_type(8))) short bf16x8;
typedef __attribute__((ext_vector_type(4))) float f32x4;

#define DEVI __device__ __forceinline__

namespace {
constexpr int BATCH = 2;
constexpr int T = 4096;
constexpr int C = 768;
constexpr int H = 12;
constexpr int HD = 64;
constexpr int M = BATCH * T;     // 8192
constexpr int N3 = 3 * C;        // 2304
constexpr int BH = BATCH * H;    // 24
}  // namespace

DEVI ushort f2b(float f) {
  union { float f; unsigned u; } v; v.f = f;
  unsigned r = (v.u + 0x7FFFu + ((v.u >> 16) & 1u)) >> 16;
  return (ushort)r;
}

__global__ __launch_bounds__(256) void cvt_kernel(const float* __restrict__ src,
                                                  ushort* __restrict__ dst, int n) {
  int i = (blockIdx.x * 256 + threadIdx.x) * 4;
  int stride = gridDim.x * 256 * 4;
  for (; i < n; i += stride) {
    float4 v = *reinterpret_cast<const float4*>(src + i);
    ushort4 o;
    o.x = f2b(v.x); o.y = f2b(v.y); o.z = f2b(v.z); o.w = f2b(v.w);
    *reinterpret_cast<ushort4*>(dst + i) = o;
  }
}

// GEMM: A [Mrows x Kd] bf16 row-major, Bm [Kd x N] bf16 row-major.
// EPI=0: scatter QKV (bias from f32, Q scaled by 0.125). EPI=1: fp32 out + bias.
template <int EPI>
__global__ __launch_bounds__(256) void gemm_kernel(
    const ushort* __restrict__ A, const ushort* __restrict__ Bm,
    const float* __restrict__ bias, int N, int Kd,
    ushort* __restrict__ qo, ushort* __restrict__ ko, ushort* __restrict__ vo,
    float* __restrict__ fo) {
  constexpr int AS = 48, BS = 48;  // LDS strides (bf16 elems): 96B, 16B-aligned, 4-way max conflict
  __shared__ ushort As[64 * AS];
  __shared__ ushort Bs[64 * BS];
  const int tid = threadIdx.x;
  const int lane = tid & 63;
  const int w = tid >> 6;
  const int c = lane & 15, g = lane >> 4;
  const int wm = w >> 1, wn = w & 1;
  const int m0 = blockIdx.y * 64, n0 = blockIdx.x * 64;

  f32x4 acc[2][2] = {};

  const int arow = tid >> 2, acol = (tid & 3) * 8;
  const int brow = tid >> 3, bcol = (tid & 7) * 8;

  for (int k0 = 0; k0 < Kd; k0 += 32) {
    __syncthreads();
    // stage A tile 64x32 (row-major)
    bf16x8 va = *reinterpret_cast<const bf16x8*>(A + (size_t)(m0 + arow) * Kd + k0 + acol);
    *reinterpret_cast<bf16x8*>(&As[arow * AS + acol]) = va;
    // stage B tile 32x64, transposed into Bs[n][k]
    bf16x8 vb = *reinterpret_cast<const bf16x8*>(Bm + (size_t)(k0 + brow) * N + n0 + bcol);
#pragma unroll
    for (int i = 0; i < 8; i++) Bs[(bcol + i) * BS + brow] = (ushort)vb[i];
    __syncthreads();

    bf16x8 af[2], bfr[2];
#pragma unroll
    for (int mi = 0; mi < 2; mi++)
      af[mi] = *reinterpret_cast<const bf16x8*>(&As[(wm * 32 + mi * 16 + c) * AS + g * 8]);
#pragma unroll
    for (int ni = 0; ni < 2; ni++)
      bfr[ni] = *reinterpret_cast<const bf16x8*>(&Bs[(wn * 32 + ni * 16 + c) * BS + g * 8]);
#pragma unroll
    for (int mi = 0; mi < 2; mi++)
#pragma unroll
      for (int ni = 0; ni < 2; ni++)
        acc[mi][ni] = __builtin_amdgcn_mfma_f32_16x16x32_bf16(af[mi], bfr[ni], acc[mi][ni], 0, 0, 0);
  }

#pragma unroll
  for (int mi = 0; mi < 2; mi++)
#pragma unroll
    for (int ni = 0; ni < 2; ni++) {
      const int n = n0 + wn * 32 + ni * 16 + c;
      const float bv = bias[n];
#pragma unroll
      for (int r = 0; r < 4; r++) {
        const int m = m0 + wm * 32 + mi * 16 + g * 4 + r;
        float val = acc[mi][ni][r] + bv;
        if (EPI == 0) {
          int part = (n >= 1536) ? 2 : (n >= 768 ? 1 : 0);
          int ci = n - part * 768;
          int hh = ci >> 6, d = ci & 63;
          int b = m >> 12, t = m & (T - 1);
          size_t idx = ((size_t)(b * H + hh) * T + t) * HD + d;
          if (part == 0) qo[idx] = f2b(val * 0.125f);       // fold 1/sqrt(64) into Q
          else if (part == 1) ko[idx] = f2b(val);
          else vo[idx] = f2b(val);
        } else {
          fo[(size_t)m * N + n] = val;
        }
      }
    }
}

// Flash attention: grid (T/64, B*H), 256 threads = 4 waves x 16 q-rows.
__global__ __launch_bounds__(256) void attn_kernel(
    const ushort* __restrict__ Qg, const ushort* __restrict__ Kg,
    const ushort* __restrict__ Vg, ushort* __restrict__ Yg) {
  constexpr int KS = 72;  // K tile stride (144B): 2-way conflict on b128 reads
  constexpr int VS = 48;  // V^T stride (96B)
  constexpr int PS = 48;  // P stride
  __shared__ ushort Ks[32 * KS];
  __shared__ ushort Vt[64 * VS];
  __shared__ ushort Pl[4 * 16 * PS];

  const int tid = threadIdx.x;
  const int lane = tid & 63;
  const int w = tid >> 6;
  const int c = lane & 15, g = lane >> 4;
  const int bh = blockIdx.y;
  const int q0 = ((int)gridDim.x - 1 - (int)blockIdx.x) * 64;  // heavy blocks first
  const int b = bh / H, h = bh % H;

  const ushort* Qp = Qg + (size_t)bh * T * HD;
  const ushort* Kp = Kg + (size_t)bh * T * HD;
  const ushort* Vp = Vg + (size_t)bh * T * HD;

  // Q fragments for this wave's 16 rows (pre-scaled by 1/8)
  bf16x8 qf[2];
#pragma unroll
  for (int s = 0; s < 2; s++)
    qf[s] = *reinterpret_cast<const bf16x8*>(Qp + (size_t)(q0 + w * 16 + c) * HD + s * 32 + g * 8);

  float mrow[4], lrow[4];
  f32x4 oacc[4] = {};
#pragma unroll
  for (int r = 0; r < 4; r++) { mrow[r] = -1e30f; lrow[r] = 0.f; }

  const int qmax_w = q0 + w * 16 + 15;
  const int nkt = q0 / 32 + 2;
  const int srow = tid >> 3, scol = (tid & 7) * 8;

  for (int kt = 0; kt < nkt; kt++) {
    const int kv0 = kt * 32;
    __syncthreads();
    {
      bf16x8 kv = *reinterpret_cast<const bf16x8*>(Kp + (size_t)(kv0 + srow) * HD + scol);
      *reinterpret_cast<bf16x8*>(&Ks[srow * KS + scol]) = kv;
      bf16x8 vv = *reinterpret_cast<const bf16x8*>(Vp + (size_t)(kv0 + srow) * HD + scol);
#pragma unroll
      for (int i = 0; i < 8; i++) Vt[(scol + i) * VS + srow] = (ushort)vv[i];
    }
    __syncthreads();
    if (kv0 > qmax_w) continue;  // fully masked for this wave (barrier count unchanged)

    // S = Q K^T : two 16x16 accs (kv halves), K-dim 64 = 2 MFMA steps
    f32x4 s[2] = {};
#pragma unroll
    for (int half = 0; half < 2; half++)
#pragma unroll
      for (int st = 0; st < 2; st++) {
        bf16x8 kf = *reinterpret_cast<const bf16x8*>(&Ks[(half * 16 + c) * KS + st * 32 + g * 8]);
        s[half] = __builtin_amdgcn_mfma_f32_16x16x32_bf16(qf[st], kf, s[half], 0, 0, 0);
      }

    // causal mask: kv = kv0 + half*16 + c ; q = q0 + w*16 + g*4 + r
#pragma unroll
    for (int half = 0; half < 2; half++) {
      const int kv = kv0 + half * 16 + c;
#pragma unroll
      for (int r = 0; r < 4; r++) {
        const int q = q0 + w * 16 + g * 4 + r;
        if (kv > q) s[half][r] = -1e30f;
      }
    }

    // online softmax, rows live across the 16 lanes with same g
    float corr[4];
#pragma unroll
    for (int r = 0; r < 4; r++) {
      float v = fmaxf(s[0][r], s[1][r]);
      v = fmaxf(v, __shfl_xor(v, 1));
      v = fmaxf(v, __shfl_xor(v, 2));
      v = fmaxf(v, __shfl_xor(v, 4));
      v = fmaxf(v, __shfl_xor(v, 8));
      const float mnew = fmaxf(mrow[r], v);
      corr[r] = __expf(mrow[r] - mnew);
      mrow[r] = mnew;
    }
    float ps[2][4];
#pragma unroll
    for (int half = 0; half < 2; half++)
#pragma unroll
      for (int r = 0; r < 4; r++) ps[half][r] = __expf(s[half][r] - mrow[r]);
#pragma unroll
    for (int r = 0; r < 4; r++) {
      float sum = ps[0][r] + ps[1][r];
      sum += __shfl_xor(sum, 1);
      sum += __shfl_xor(sum, 2);
      sum += __shfl_xor(sum, 4);
      sum += __shfl_xor(sum, 8);
      lrow[r] = lrow[r] * corr[r] + sum;
    }
#pragma unroll
    for (int dt = 0; dt < 4; dt++)
#pragma unroll
      for (int r = 0; r < 4; r++) oacc[dt][r] *= corr[r];

    // P -> LDS (per-wave region), then consume as A-fragment
    ushort* Pw = &Pl[w * 16 * PS];
#pragma unroll
    for (int half = 0; half < 2; half++)
#pragma unroll
      for (int r = 0; r < 4; r++)
        Pw[(g * 4 + r) * PS + half * 16 + c] = f2b(ps[half][r]);
    const bf16x8 pf = *reinterpret_cast<const bf16x8*>(&Pw[c * PS + g * 8]);
#pragma unroll
    for (int dt = 0; dt < 4; dt++) {
      bf16x8 vf = *reinterpret_cast<const bf16x8*>(&Vt[(dt * 16 + c) * VS + g * 8]);
      oacc[dt] = __builtin_amdgcn_mfma_f32_16x16x32_bf16(pf, vf, oacc[dt], 0, 0, 0);
    }
  }

  // write Y[b*T + q][h*64 + d] bf16
#pragma unroll
  for (int r = 0; r < 4; r++) {
    const int q = q0 + w * 16 + g * 4 + r;
    const float inv = 1.0f / lrow[r];
#pragma unroll
    for (int dt = 0; dt < 4; dt++)
      Yg[((size_t)(b * T + q)) * C + h * 64 + dt * 16 + c] = f2b(oacc[dt][r] * inv);
  }
}

extern "C" void kernel_launch(void* const* d_in, const int* in_sizes, int n_in,
                              void* d_out, int out_size, void* d_ws, size_t ws_size,
                              hipStream_t stream) {
  const float* x = (const float*)d_in[0];
  const float* Wa = (const float*)d_in[1];
  const float* ba = (const float*)d_in[2];
  const float* Wp = (const float*)d_in[3];
  const float* bp = (const float*)d_in[4];
  float* out = (float*)d_out;

  char* ws = (char*)d_ws;
  size_t off = 0;
  auto carve = [&](size_t bytes) {
    void* p = ws + off;
    off += (bytes + 255) & ~(size_t)255;
    return p;
  };
  ushort* xb  = (ushort*)carve((size_t)M * C * 2);
  ushort* Wab = (ushort*)carve((size_t)C * N3 * 2);
  ushort* Wpb = (ushort*)carve((size_t)C * C * 2);
  ushort* Qb  = (ushort*)carve((size_t)BH * T * HD * 2);
  ushort* Kb  = (ushort*)carve((size_t)BH * T * HD * 2);
  ushort* Vb  = (ushort*)carve((size_t)BH * T * HD * 2);
  ushort* Yb  = (ushort*)carve((size_t)M * C * 2);

  cvt_kernel<<<2048, 256, 0, stream>>>(x, xb, M * C);
  cvt_kernel<<<1024, 256, 0, stream>>>(Wa, Wab, C * N3);
  cvt_kernel<<<576, 256, 0, stream>>>(Wp, Wpb, C * C);

  gemm_kernel<0><<<dim3(N3 / 64, M / 64), 256, 0, stream>>>(
      xb, Wab, ba, N3, C, Qb, Kb, Vb, nullptr);

  attn_kernel<<<dim3(T / 64, BH), 256, 0, stream>>>(Qb, Kb, Vb, Yb);

  gemm_kernel<1><<<dim3(C / 64, M / 64), 256, 0, stream>>>(
      Yb, Wpb, bp, C, C, nullptr, nullptr, nullptr, out);
}

// Round 2
// 366.404 us; speedup vs baseline: 2.0806x; 2.0806x over previous
//
#include <hip/hip_runtime.h>
#include <hip/hip_bf16.h>

typedef __attribute__((ext_vector_type(8))) short bf16x8;
typedef __attribute__((ext_vector_type(4))) float f32x4;
typedef __attribute__((ext_vector_type(4))) int i32x4;

#define DEVI __device__ __forceinline__

namespace {
constexpr int BATCH = 2;
constexpr int T = 4096;
constexpr int C = 768;
constexpr int H = 12;
constexpr int HD = 64;
constexpr int M = BATCH * T;     // 8192
constexpr int N3 = 3 * C;        // 2304
constexpr int BH = BATCH * H;    // 24
constexpr float QSCALE = 0.125f * 1.44269504088896f;  // 1/sqrt(64) * log2(e)
}  // namespace

DEVI ushort f2b(float f) {
  union { float f; unsigned u; } v; v.f = f;
  unsigned r = (v.u + 0x7FFFu + ((v.u >> 16) & 1u)) >> 16;
  return (ushort)r;
}

__global__ __launch_bounds__(256) void cvt_kernel(const float* __restrict__ src,
                                                  ushort* __restrict__ dst, int n) {
  int i = (blockIdx.x * 256 + threadIdx.x) * 4;
  int stride = gridDim.x * 256 * 4;
  for (; i < n; i += stride) {
    float4 v = *reinterpret_cast<const float4*>(src + i);
    ushort4 o;
    o.x = f2b(v.x); o.y = f2b(v.y); o.z = f2b(v.z); o.w = f2b(v.w);
    *reinterpret_cast<ushort4*>(dst + i) = o;
  }
}

// GEMM: A [Mrows x Kd] bf16 row-major, Bm [Kd x N] bf16 row-major.
// EPI=0: scatter QKV (bias from f32, Q scaled by QSCALE). EPI=1: fp32 out + bias.
template <int EPI>
__global__ __launch_bounds__(256) void gemm_kernel(
    const ushort* __restrict__ A, const ushort* __restrict__ Bm,
    const float* __restrict__ bias, int N, int Kd,
    ushort* __restrict__ qo, ushort* __restrict__ ko, ushort* __restrict__ vo,
    float* __restrict__ fo) {
  constexpr int AS = 48, BS = 48;
  __shared__ ushort As[64 * AS];
  __shared__ ushort Bs[64 * BS];
  const int tid = threadIdx.x;
  const int lane = tid & 63;
  const int w = tid >> 6;
  const int c = lane & 15, g = lane >> 4;
  const int wm = w >> 1, wn = w & 1;
  const int m0 = blockIdx.y * 64, n0 = blockIdx.x * 64;

  f32x4 acc[2][2] = {};

  const int arow = tid >> 2, acol = (tid & 3) * 8;
  const int brow = tid >> 3, bcol = (tid & 7) * 8;

  for (int k0 = 0; k0 < Kd; k0 += 32) {
    __syncthreads();
    bf16x8 va = *reinterpret_cast<const bf16x8*>(A + (size_t)(m0 + arow) * Kd + k0 + acol);
    *reinterpret_cast<bf16x8*>(&As[arow * AS + acol]) = va;
    bf16x8 vb = *reinterpret_cast<const bf16x8*>(Bm + (size_t)(k0 + brow) * N + n0 + bcol);
#pragma unroll
    for (int i = 0; i < 8; i++) Bs[(bcol + i) * BS + brow] = (ushort)vb[i];
    __syncthreads();

    bf16x8 af[2], bfr[2];
#pragma unroll
    for (int mi = 0; mi < 2; mi++)
      af[mi] = *reinterpret_cast<const bf16x8*>(&As[(wm * 32 + mi * 16 + c) * AS + g * 8]);
#pragma unroll
    for (int ni = 0; ni < 2; ni++)
      bfr[ni] = *reinterpret_cast<const bf16x8*>(&Bs[(wn * 32 + ni * 16 + c) * BS + g * 8]);
#pragma unroll
    for (int mi = 0; mi < 2; mi++)
#pragma unroll
      for (int ni = 0; ni < 2; ni++)
        acc[mi][ni] = __builtin_amdgcn_mfma_f32_16x16x32_bf16(af[mi], bfr[ni], acc[mi][ni], 0, 0, 0);
  }

#pragma unroll
  for (int mi = 0; mi < 2; mi++)
#pragma unroll
    for (int ni = 0; ni < 2; ni++) {
      const int n = n0 + wn * 32 + ni * 16 + c;
      const float bv = bias[n];
#pragma unroll
      for (int r = 0; r < 4; r++) {
        const int m = m0 + wm * 32 + mi * 16 + g * 4 + r;
        float val = acc[mi][ni][r] + bv;
        if (EPI == 0) {
          int part = (n >= 1536) ? 2 : (n >= 768 ? 1 : 0);
          int ci = n - part * 768;
          int hh = ci >> 6, d = ci & 63;
          int b = m >> 12, t = m & (T - 1);
          size_t idx = ((size_t)(b * H + hh) * T + t) * HD + d;
          if (part == 0) qo[idx] = f2b(val * QSCALE);
          else if (part == 1) ko[idx] = f2b(val);
          else vo[idx] = f2b(val);
        } else {
          fo[(size_t)m * N + n] = val;
        }
      }
    }
}

// Flash attention, swapped-QK layout.
// Grid (32, 24): block bx handles q-tiles bx and 63-bx -> 65 kv-tiles each (balanced).
// 256 threads = 4 waves x 16 q-rows. KVBLK=64.
__global__ __launch_bounds__(256) void attn_kernel(
    const ushort* __restrict__ Qg, const ushort* __restrict__ Kg,
    const ushort* __restrict__ Vg, ushort* __restrict__ Yg) {
  constexpr int KSTR = 68;  // 136B stride: <=2-way conflicts on b128 reads
  __shared__ ushort Ks[64 * KSTR];  // K row-major [kv][k]
  __shared__ ushort Vt[64 * KSTR];  // V transposed [d][kv]

  const int tid = threadIdx.x;
  const int lane = tid & 63;
  const int w = tid >> 6;
  const int c = lane & 15, g = lane >> 4;
  const int bh = blockIdx.y;
  const int b = bh / H, h = bh % H;

  const ushort* Qp = Qg + (size_t)bh * T * HD;
  const ushort* Kp = Kg + (size_t)bh * T * HD;
  const ushort* Vp = Vg + (size_t)bh * T * HD;

  const bool ghi = (g >> 1) != 0;
  const int addrA = ((g & 1) * 32 + c) * 4;  // src lane for A-frag dwords 0,1
  const int addrB = addrA + 64;              // dwords 2,3
  const int addrO = g * 16;                  // + 4*r : src lane g*4+r (holds q_local=g*4+r stats)

  const int krow = tid >> 3, kcol = (tid & 7) * 8;

  for (int pass = 0; pass < 2; pass++) {
    const int qt = (pass == 0) ? (int)blockIdx.x : (63 - (int)blockIdx.x);
    const int q0 = qt * 64;
    const int qme = q0 + w * 16 + c;  // this lane's q row (softmax state)

    bf16x8 qf[2];
#pragma unroll
    for (int ks2 = 0; ks2 < 2; ks2++)
      qf[ks2] = *reinterpret_cast<const bf16x8*>(
          Qp + (size_t)(q0 + w * 16 + c) * HD + ks2 * 32 + g * 8);

    float mrun = -1e30f, lrun = 0.f;
    f32x4 oacc[4] = {};

    for (int kt = 0; kt <= qt; kt++) {
      const int kv0 = kt * 64;
      __syncthreads();
#pragma unroll
      for (int it = 0; it < 2; it++) {
        // K: row-major b128 stage (coalesced)
        bf16x8 kvv = *reinterpret_cast<const bf16x8*>(
            Kp + (size_t)(kv0 + krow + 32 * it) * HD + kcol);
        *reinterpret_cast<bf16x8*>(&Ks[(krow + 32 * it) * KSTR + kcol]) = kvv;
        // V: transpose-stage; kv=lane => write banks spread (2-way max)
        const int dblk = w + 4 * it;
        bf16x8 vv = *reinterpret_cast<const bf16x8*>(
            Vp + (size_t)(kv0 + lane) * HD + dblk * 8);
#pragma unroll
        for (int k = 0; k < 8; k++) Vt[(dblk * 8 + k) * KSTR + lane] = (ushort)vv[k];
      }
      __syncthreads();

      // S^T = K x Q^T : lane holds S^T[kv=q4*16+g*4+r][q=c]
      f32x4 s[4] = {};
#pragma unroll
      for (int q4 = 0; q4 < 4; q4++)
#pragma unroll
        for (int ks2 = 0; ks2 < 2; ks2++) {
          bf16x8 kf = *reinterpret_cast<const bf16x8*>(
              &Ks[(q4 * 16 + c) * KSTR + ks2 * 32 + g * 8]);
          s[q4] = __builtin_amdgcn_mfma_f32_16x16x32_bf16(kf, qf[ks2], s[q4], 0, 0, 0);
        }

      if (kt == qt) {  // only the diagonal tile needs masking
#pragma unroll
        for (int q4 = 0; q4 < 4; q4++)
#pragma unroll
          for (int r = 0; r < 4; r++) {
            const int kvv = kv0 + q4 * 16 + g * 4 + r;
            if (kvv > qme) s[q4][r] = -1e30f;
          }
      }

      // online softmax: per-lane row q=c; reduce over g via 2 shfls
      float pm = -1e30f;
#pragma unroll
      for (int q4 = 0; q4 < 4; q4++)
#pragma unroll
        for (int r = 0; r < 4; r++) pm = fmaxf(pm, s[q4][r]);
      pm = fmaxf(pm, __shfl_xor(pm, 16));
      pm = fmaxf(pm, __shfl_xor(pm, 32));
      const float mnew = fmaxf(mrun, pm);
      const bool ch = mnew > mrun;
      float sum = 0.f;
#pragma unroll
      for (int q4 = 0; q4 < 4; q4++)
#pragma unroll
        for (int r = 0; r < 4; r++) {
          const float p = exp2f(s[q4][r] - mnew);
          s[q4][r] = p;
          sum += p;
        }
      sum += __shfl_xor(sum, 16);
      sum += __shfl_xor(sum, 32);
      if (__any(ch)) {
        const float corr = exp2f(mrun - mnew);
        lrun = lrun * corr + sum;
        const int ci = __float_as_int(corr);
#pragma unroll
        for (int r = 0; r < 4; r++) {
          const float co = __int_as_float(__builtin_amdgcn_ds_bpermute(addrO + 4 * r, ci));
#pragma unroll
          for (int dt = 0; dt < 4; dt++) oacc[dt][r] *= co;
        }
      } else {
        lrun += sum;
      }
      mrun = mnew;

      // P (f32, S^T layout) -> bf16 pairs in-register
      int pkv[4][2];
#pragma unroll
      for (int q4 = 0; q4 < 4; q4++)
#pragma unroll
        for (int pr = 0; pr < 2; pr++)
          asm("v_cvt_pk_bf16_f32 %0, %1, %2"
              : "=v"(pkv[q4][pr])
              : "v"(s[q4][2 * pr]), "v"(s[q4][2 * pr + 1]));

      // Build PV A-fragment (P[q=c][kv]) via bpermute, then PV MFMAs
#pragma unroll
      for (int kstep = 0; kstep < 2; kstep++) {
        int fA, fB, a0, a1, a2, a3;
        fA = __builtin_amdgcn_ds_bpermute(addrA, pkv[kstep * 2][0]);
        fB = __builtin_amdgcn_ds_bpermute(addrA, pkv[kstep * 2 + 1][0]);
        a0 = ghi ? fB : fA;
        fA = __builtin_amdgcn_ds_bpermute(addrA, pkv[kstep * 2][1]);
        fB = __builtin_amdgcn_ds_bpermute(addrA, pkv[kstep * 2 + 1][1]);
        a1 = ghi ? fB : fA;
        fA = __builtin_amdgcn_ds_bpermute(addrB, pkv[kstep * 2][0]);
        fB = __builtin_amdgcn_ds_bpermute(addrB, pkv[kstep * 2 + 1][0]);
        a2 = ghi ? fB : fA;
        fA = __builtin_amdgcn_ds_bpermute(addrB, pkv[kstep * 2][1]);
        fB = __builtin_amdgcn_ds_bpermute(addrB, pkv[kstep * 2 + 1][1]);
        a3 = ghi ? fB : fA;
        i32x4 ai = {a0, a1, a2, a3};
        bf16x8 af = __builtin_bit_cast(bf16x8, ai);
#pragma unroll
        for (int dt = 0; dt < 4; dt++) {
          bf16x8 vf = *reinterpret_cast<const bf16x8*>(
              &Vt[(dt * 16 + c) * KSTR + kstep * 32 + g * 8]);
          oacc[dt] = __builtin_amdgcn_mfma_f32_16x16x32_bf16(af, vf, oacc[dt], 0, 0, 0);
        }
      }
    }  // kt

    // epilogue: O rows are q=g*4+r; fetch 1/l from lane g*4+r
    const float linv = 1.0f / lrun;
    const int li = __float_as_int(linv);
#pragma unroll
    for (int r = 0; r < 4; r++) {
      const float lo = __int_as_float(__builtin_amdgcn_ds_bpermute(addrO + 4 * r, li));
      const int q = q0 + w * 16 + g * 4 + r;
#pragma unroll
      for (int dt = 0; dt < 4; dt++)
        Yg[((size_t)(b * T + q)) * C + h * 64 + dt * 16 + c] = f2b(oacc[dt][r] * lo);
    }
  }  // pass
}

extern "C" void kernel_launch(void* const* d_in, const int* in_sizes, int n_in,
                              void* d_out, int out_size, void* d_ws, size_t ws_size,
                              hipStream_t stream) {
  const float* x = (const float*)d_in[0];
  const float* Wa = (const float*)d_in[1];
  const float* ba = (const float*)d_in[2];
  const float* Wp = (const float*)d_in[3];
  const float* bp = (const float*)d_in[4];
  float* out = (float*)d_out;

  char* ws = (char*)d_ws;
  size_t off = 0;
  auto carve = [&](size_t bytes) {
    void* p = ws + off;
    off += (bytes + 255) & ~(size_t)255;
    return p;
  };
  ushort* xb  = (ushort*)carve((size_t)M * C * 2);
  ushort* Wab = (ushort*)carve((size_t)C * N3 * 2);
  ushort* Wpb = (ushort*)carve((size_t)C * C * 2);
  ushort* Qb  = (ushort*)carve((size_t)BH * T * HD * 2);
  ushort* Kb  = (ushort*)carve((size_t)BH * T * HD * 2);
  ushort* Vb  = (ushort*)carve((size_t)BH * T * HD * 2);
  ushort* Yb  = (ushort*)carve((size_t)M * C * 2);

  cvt_kernel<<<2048, 256, 0, stream>>>(x, xb, M * C);
  cvt_kernel<<<1024, 256, 0, stream>>>(Wa, Wab, C * N3);
  cvt_kernel<<<576, 256, 0, stream>>>(Wp, Wpb, C * C);

  gemm_kernel<0><<<dim3(N3 / 64, M / 64), 256, 0, stream>>>(
      xb, Wab, ba, N3, C, Qb, Kb, Vb, nullptr);

  attn_kernel<<<dim3(32, BH), 256, 0, stream>>>(Qb, Kb, Vb, Yb);

  gemm_kernel<1><<<dim3(C / 64, M / 64), 256, 0, stream>>>(
      Yb, Wpb, bp, C, C, nullptr, nullptr, nullptr, out);
}

// Round 3
// 361.760 us; speedup vs baseline: 2.1073x; 1.0128x over previous
//
#include <hip/hip_runtime.h>
#include <hip/hip_bf16.h>

typedef __attribute__((ext_vector_type(8))) short bf16x8;
typedef __attribute__((ext_vector_type(4))) float f32x4;
typedef __attribute__((ext_vector_type(16))) float f32x16;
typedef __attribute__((ext_vector_type(4))) int i32x4;

#define DEVI __device__ __forceinline__

namespace {
constexpr int BATCH = 2;
constexpr int T = 4096;
constexpr int C = 768;
constexpr int H = 12;
constexpr int HD = 64;
constexpr int M = BATCH * T;     // 8192
constexpr int N3 = 3 * C;        // 2304
constexpr int BH = BATCH * H;    // 24
constexpr float QSCALE = 0.125f * 1.44269504088896f;  // 1/sqrt(64) * log2(e)
}  // namespace

DEVI ushort f2b(float f) {
  union { float f; unsigned u; } v; v.f = f;
  unsigned r = (v.u + 0x7FFFu + ((v.u >> 16) & 1u)) >> 16;
  return (ushort)r;
}

DEVI f32x16 zero16() {
  f32x16 z;
#pragma unroll
  for (int i = 0; i < 16; i++) z[i] = 0.f;
  return z;
}

// async 16B global->LDS. LDS dest is wave-uniform base; HW adds lane*16.
DEVI void gload16(const void* g, void* l) {
  __builtin_amdgcn_global_load_lds(
      (const __attribute__((address_space(1))) unsigned int*)g,
      (__attribute__((address_space(3))) unsigned int*)l, 16, 0, 0);
}

__global__ __launch_bounds__(256) void cvt_kernel(const float* __restrict__ src,
                                                  ushort* __restrict__ dst, int n) {
  int i = (blockIdx.x * 256 + threadIdx.x) * 4;
  int stride = gridDim.x * 256 * 4;
  for (; i < n; i += stride) {
    float4 v = *reinterpret_cast<const float4*>(src + i);
    ushort4 o;
    o.x = f2b(v.x); o.y = f2b(v.y); o.z = f2b(v.z); o.w = f2b(v.w);
    *reinterpret_cast<ushort4*>(dst + i) = o;
  }
}

// GEMM: A [Mrows x Kd] bf16 row-major, Bm [Kd x N] bf16 row-major.
// EPI=0: QKV epilogue: Q scaled [bh][t][d]; K swizzled [bh][t][d^]; V transposed+swizzled [bh][d][t^].
// EPI=1: fp32 out + bias.
template <int EPI>
__global__ __launch_bounds__(256) void gemm_kernel(
    const ushort* __restrict__ A, const ushort* __restrict__ Bm,
    const float* __restrict__ bias, int N, int Kd,
    ushort* __restrict__ qo, ushort* __restrict__ ko, ushort* __restrict__ vo,
    float* __restrict__ fo) {
  constexpr int AS = 48, BS = 48;
  __shared__ ushort As[64 * AS];
  __shared__ ushort Bs[64 * BS];
  const int tid = threadIdx.x;
  const int lane = tid & 63;
  const int w = tid >> 6;
  const int c = lane & 15, g = lane >> 4;
  const int wm = w >> 1, wn = w & 1;
  const int m0 = blockIdx.y * 64, n0 = blockIdx.x * 64;

  f32x4 acc[2][2] = {};

  const int arow = tid >> 2, acol = (tid & 3) * 8;
  const int brow = tid >> 3, bcol = (tid & 7) * 8;

  for (int k0 = 0; k0 < Kd; k0 += 32) {
    __syncthreads();
    bf16x8 va = *reinterpret_cast<const bf16x8*>(A + (size_t)(m0 + arow) * Kd + k0 + acol);
    *reinterpret_cast<bf16x8*>(&As[arow * AS + acol]) = va;
    bf16x8 vb = *reinterpret_cast<const bf16x8*>(Bm + (size_t)(k0 + brow) * N + n0 + bcol);
#pragma unroll
    for (int i = 0; i < 8; i++) Bs[(bcol + i) * BS + brow] = (ushort)vb[i];
    __syncthreads();

    bf16x8 af[2], bfr[2];
#pragma unroll
    for (int mi = 0; mi < 2; mi++)
      af[mi] = *reinterpret_cast<const bf16x8*>(&As[(wm * 32 + mi * 16 + c) * AS + g * 8]);
#pragma unroll
    for (int ni = 0; ni < 2; ni++)
      bfr[ni] = *reinterpret_cast<const bf16x8*>(&Bs[(wn * 32 + ni * 16 + c) * BS + g * 8]);
#pragma unroll
    for (int mi = 0; mi < 2; mi++)
#pragma unroll
      for (int ni = 0; ni < 2; ni++)
        acc[mi][ni] = __builtin_amdgcn_mfma_f32_16x16x32_bf16(af[mi], bfr[ni], acc[mi][ni], 0, 0, 0);
  }

  if constexpr (EPI == 0) {
    if (n0 >= 1536) {
      // V tile: bias, transpose via LDS, store V^T swizzled: [bh][d][t ^ ((d&7)*8) within 64-blk]
      __shared__ ushort TPV[64 * 68];
      const int hh = (n0 - 1536) >> 6;
      const int bb = m0 >> 12;
      const int t0 = m0 & (T - 1);
#pragma unroll
      for (int mi = 0; mi < 2; mi++)
#pragma unroll
        for (int ni = 0; ni < 2; ni++) {
          const int dn = wn * 32 + ni * 16 + c;
          const float bv = bias[n0 + dn];
#pragma unroll
          for (int r = 0; r < 4; r++) {
            const int tl = wm * 32 + mi * 16 + g * 4 + r;
            TPV[dn * 68 + tl] = f2b(acc[mi][ni][r] + bv);
          }
        }
      __syncthreads();
      const int d = tid >> 2;
#pragma unroll
      for (int k2 = 0; k2 < 2; k2++) {
        const int x8 = (tid & 3) * 2 + k2;
        bf16x8 vv = *reinterpret_cast<const bf16x8*>(&TPV[d * 68 + x8 * 8]);
        *reinterpret_cast<bf16x8*>(
            vo + (size_t)((bb * H + hh) * 64 + d) * T + t0 + ((x8 ^ (d & 7)) * 8)) = vv;
      }
    } else {
#pragma unroll
      for (int mi = 0; mi < 2; mi++)
#pragma unroll
        for (int ni = 0; ni < 2; ni++) {
          const int n = n0 + wn * 32 + ni * 16 + c;
          const float bv = bias[n];
#pragma unroll
          for (int r = 0; r < 4; r++) {
            const int m = m0 + wm * 32 + mi * 16 + g * 4 + r;
            const float val = acc[mi][ni][r] + bv;
            const int part = (n >= 768) ? 1 : 0;
            const int ci = n - part * 768;
            const int hh = ci >> 6, dd = ci & 63;
            const int bb = m >> 12, t = m & (T - 1);
            if (part == 0) {
              qo[((size_t)(bb * H + hh) * T + t) * HD + dd] = f2b(val * QSCALE);
            } else {
              ko[((size_t)(bb * H + hh) * T + t) * HD + (dd ^ ((t & 7) << 3))] = f2b(val);
            }
          }
        }
    }
  } else {
#pragma unroll
    for (int mi = 0; mi < 2; mi++)
#pragma unroll
      for (int ni = 0; ni < 2; ni++) {
        const int n = n0 + wn * 32 + ni * 16 + c;
        const float bv = bias[n];
#pragma unroll
        for (int r = 0; r < 4; r++) {
          const int m = m0 + wm * 32 + mi * 16 + g * 4 + r;
          fo[(size_t)m * N + n] = acc[mi][ni][r] + bv;
        }
      }
  }
}

// Flash attention v3: 32x32x16 MFMA, swapped QK^T (S^T), O^T accumulation.
// Grid (32, BH), 256 thr = 4 waves x 32 q-rows -> q-tile 128. KVBLK=64, heavy-first.
__global__ __launch_bounds__(256, 2) void attn_kernel(
    const ushort* __restrict__ Qg, const ushort* __restrict__ Kg,
    const ushort* __restrict__ Vtg, ushort* __restrict__ Yg) {
  __shared__ ushort Ks[64 * 64];   // K tile [kv][k^swz], linear for gload_lds
  __shared__ ushort Vs[64 * 64];   // V^T tile [d][kv^swz]
  __shared__ ushort Yt[128 * 68];  // O transpose-out buffer

  const int tid = threadIdx.x;
  const int lane = tid & 63;
  const int w = tid >> 6;
  const int l31 = lane & 31;
  const int hi = lane >> 5;
  const int bh = blockIdx.y;
  const int bb = bh / H, h = bh % H;
  const int qt = 31 - (int)blockIdx.x;  // heavy blocks dispatched first
  const int q0 = qt * 128;
  const int q0w = q0 + w * 32;
  const int qc = q0w + l31;  // this lane's q row (softmax state col)

  const ushort* Qp = Qg + (size_t)bh * T * HD;
  const char* Kbp = (const char*)(Kg + (size_t)bh * T * HD);
  const char* Vbp = (const char*)(Vtg + (size_t)bh * HD * T);

  // Q B-fragments: B[k=ks*16+hi*8+j][n=q=l31]
  bf16x8 qf[4];
#pragma unroll
  for (int ks = 0; ks < 4; ks++)
    qf[ks] = *reinterpret_cast<const bf16x8*>(Qp + (size_t)qc * HD + ks * 16 + hi * 8);

  float mrun = -1e30f, lrun = 0.f;
  f32x16 o16[2];  // O^T accum: d = dt*32 + crow(r,hi), q = l31
  o16[0] = zero16();
  o16[1] = zero16();

  const int vrow = w * 16 + (lane >> 3);
  const int nkt = 2 * qt + 2;

  for (int kt = 0; kt < nkt; kt++) {
    const int kv0 = kt * 64;
    __syncthreads();
#pragma unroll
    for (int c2 = 0; c2 < 2; c2++) {
      const int blk = w * 2 + c2;
      gload16(Kbp + (size_t)kv0 * 128 + blk * 1024 + lane * 16, (char*)Ks + blk * 1024);
      gload16(Vbp + ((size_t)(vrow + c2 * 8) * T + kv0) * 2 + (lane & 7) * 16,
              (char*)Vs + blk * 1024);
    }
    __syncthreads();

    const bool have[2] = {kv0 <= q0w + 31, kv0 + 32 <= q0w + 31};
    const bool needm[2] = {kv0 + 31 > q0w, kv0 + 63 > q0w};

    // S^T = K x Q^T : per sub, lane holds S^T[kv = kv0+sub*32+crow(r,hi)][q=l31]
    f32x16 s2[2];
#pragma unroll
    for (int sub = 0; sub < 2; sub++) {
      if (!have[sub]) continue;
      f32x16 sacc = zero16();
      const int row = sub * 32 + l31;
      const int sw = (row & 7) << 3;
#pragma unroll
      for (int ks = 0; ks < 4; ks++) {
        bf16x8 kf = *reinterpret_cast<const bf16x8*>(&Ks[row * 64 + ((ks * 16 + hi * 8) ^ sw)]);
        sacc = __builtin_amdgcn_mfma_f32_32x32x16_bf16(kf, qf[ks], sacc, 0, 0, 0);
      }
      if (needm[sub]) {
#pragma unroll
        for (int r = 0; r < 16; r++) {
          const int kv = kv0 + sub * 32 + (r & 3) + ((r >> 2) << 3) + (hi << 2);
          if (kv > qc) sacc[r] = -1e30f;
        }
      }
      s2[sub] = sacc;
    }

    // online softmax: per-lane (q = l31); one cross shuffle (lane^32 holds other kv half)
    float pm = -1e30f;
#pragma unroll
    for (int sub = 0; sub < 2; sub++) {
      if (!have[sub]) continue;
#pragma unroll
      for (int r = 0; r < 16; r++) pm = fmaxf(pm, s2[sub][r]);
    }
    pm = fmaxf(pm, __shfl_xor(pm, 32));
    const float mnew = fmaxf(mrun, pm);
    float sum = 0.f;
#pragma unroll
    for (int sub = 0; sub < 2; sub++) {
      if (!have[sub]) continue;
#pragma unroll
      for (int r = 0; r < 16; r++) {
        const float p = exp2f(s2[sub][r] - mnew);
        s2[sub][r] = p;
        sum += p;
      }
    }
    sum += __shfl_xor(sum, 32);
    if (__any(mnew > mrun)) {
      const float corr = exp2f(mrun - mnew);
      lrun = lrun * corr + sum;
#pragma unroll
      for (int dt = 0; dt < 2; dt++)
#pragma unroll
        for (int r = 0; r < 16; r++) o16[dt][r] *= corr;
    } else {
      lrun += sum;
    }
    mrun = mnew;

    // P^T B-frag in-register (cvt_pk + permlane32_swap), then O^T += V^T x P^T
#pragma unroll
    for (int sub = 0; sub < 2; sub++) {
      if (!have[sub]) continue;
#pragma unroll
      for (int ks2 = 0; ks2 < 2; ks2++) {
        const int r0 = ks2 * 8;
        int a0, a1, b0, b1;
        asm("v_cvt_pk_bf16_f32 %0, %1, %2" : "=v"(a0) : "v"(s2[sub][r0 + 0]), "v"(s2[sub][r0 + 1]));
        asm("v_cvt_pk_bf16_f32 %0, %1, %2" : "=v"(a1) : "v"(s2[sub][r0 + 2]), "v"(s2[sub][r0 + 3]));
        asm("v_cvt_pk_bf16_f32 %0, %1, %2" : "=v"(b0) : "v"(s2[sub][r0 + 4]), "v"(s2[sub][r0 + 5]));
        asm("v_cvt_pk_bf16_f32 %0, %1, %2" : "=v"(b1) : "v"(s2[sub][r0 + 6]), "v"(s2[sub][r0 + 7]));
        asm("v_permlane32_swap_b32 %0, %1" : "+v"(a0), "+v"(b0));
        asm("v_permlane32_swap_b32 %0, %1" : "+v"(a1), "+v"(b1));
        const i32x4 pi = {a0, a1, b0, b1};
        const bf16x8 pf = __builtin_bit_cast(bf16x8, pi);
#pragma unroll
        for (int dt = 0; dt < 2; dt++) {
          const int drow = dt * 32 + l31;
          const int sw = (drow & 7) << 3;
          bf16x8 vf = *reinterpret_cast<const bf16x8*>(
              &Vs[drow * 64 + ((sub * 32 + ks2 * 16 + hi * 8) ^ sw)]);
          o16[dt] = __builtin_amdgcn_mfma_f32_32x32x16_bf16(vf, pf, o16[dt], 0, 0, 0);
        }
      }
    }
  }  // kt

  // epilogue: O^T -> LDS transpose -> coalesced Y write
  const float linv = 1.0f / lrun;
#pragma unroll
  for (int dt = 0; dt < 2; dt++)
#pragma unroll
    for (int r = 0; r < 16; r++) {
      const int d = dt * 32 + (r & 3) + ((r >> 2) << 3) + (hi << 2);
      Yt[(w * 32 + l31) * 68 + d] = f2b(o16[dt][r] * linv);
    }
  __syncthreads();
  {
    const int row = tid >> 1;
    const int half = tid & 1;
#pragma unroll
    for (int seg = 0; seg < 4; seg++) {
      bf16x8 vv = *reinterpret_cast<const bf16x8*>(&Yt[row * 68 + half * 32 + seg * 8]);
      *reinterpret_cast<bf16x8*>(
          Yg + ((size_t)(bb * T + q0 + row)) * C + h * 64 + half * 32 + seg * 8) = vv;
    }
  }
}

extern "C" void kernel_launch(void* const* d_in, const int* in_sizes, int n_in,
                              void* d_out, int out_size, void* d_ws, size_t ws_size,
                              hipStream_t stream) {
  const float* x = (const float*)d_in[0];
  const float* Wa = (const float*)d_in[1];
  const float* ba = (const float*)d_in[2];
  const float* Wp = (const float*)d_in[3];
  const float* bp = (const float*)d_in[4];
  float* out = (float*)d_out;

  char* ws = (char*)d_ws;
  size_t off = 0;
  auto carve = [&](size_t bytes) {
    void* p = ws + off;
    off += (bytes + 255) & ~(size_t)255;
    return p;
  };
  ushort* xb  = (ushort*)carve((size_t)M * C * 2);
  ushort* Wab = (ushort*)carve((size_t)C * N3 * 2);
  ushort* Wpb = (ushort*)carve((size_t)C * C * 2);
  ushort* Qb  = (ushort*)carve((size_t)BH * T * HD * 2);
  ushort* Kb  = (ushort*)carve((size_t)BH * T * HD * 2);
  ushort* Vtb = (ushort*)carve((size_t)BH * HD * T * 2);
  ushort* Yb  = (ushort*)carve((size_t)M * C * 2);

  cvt_kernel<<<2048, 256, 0, stream>>>(x, xb, M * C);
  cvt_kernel<<<1024, 256, 0, stream>>>(Wa, Wab, C * N3);
  cvt_kernel<<<576, 256, 0, stream>>>(Wp, Wpb, C * C);

  gemm_kernel<0><<<dim3(N3 / 64, M / 64), 256, 0, stream>>>(
      xb, Wab, ba, N3, C, Qb, Kb, Vtb, nullptr);

  attn_kernel<<<dim3(32, BH), 256, 0, stream>>>(Qb, Kb, Vtb, Yb);

  gemm_kernel<1><<<dim3(C / 64, M / 64), 256, 0, stream>>>(
      Yb, Wpb, bp, C, C, nullptr, nullptr, nullptr, out);
}

// Round 4
// 331.680 us; speedup vs baseline: 2.2984x; 1.0907x over previous
//
#include <hip/hip_runtime.h>
#include <hip/hip_bf16.h>

typedef __attribute__((ext_vector_type(8))) short bf16x8;
typedef __attribute__((ext_vector_type(4))) float f32x4;
typedef __attribute__((ext_vector_type(16))) float f32x16;
typedef __attribute__((ext_vector_type(4))) int i32x4;

#define DEVI __device__ __forceinline__

namespace {
constexpr int BATCH = 2;
constexpr int T = 4096;
constexpr int C = 768;
constexpr int H = 12;
constexpr int HD = 64;
constexpr int M = BATCH * T;     // 8192
constexpr int N3 = 3 * C;        // 2304
constexpr int BH = BATCH * H;    // 24
constexpr float QSCALE = 0.125f * 1.44269504088896f;  // 1/sqrt(64) * log2(e)
}  // namespace

DEVI ushort f2b(float f) {
  union { float f; unsigned u; } v; v.f = f;
  unsigned r = (v.u + 0x7FFFu + ((v.u >> 16) & 1u)) >> 16;
  return (ushort)r;
}

DEVI f32x16 zero16() {
  f32x16 z;
#pragma unroll
  for (int i = 0; i < 16; i++) z[i] = 0.f;
  return z;
}

// async 16B global->LDS. LDS dest is wave-uniform base; HW adds lane*16.
DEVI void gload16(const void* g, void* l) {
  __builtin_amdgcn_global_load_lds(
      (const __attribute__((address_space(1))) unsigned int*)g,
      (__attribute__((address_space(3))) unsigned int*)l, 16, 0, 0);
}

__global__ __launch_bounds__(256) void cvt_kernel(const float* __restrict__ src,
                                                  ushort* __restrict__ dst, int n) {
  int i = (blockIdx.x * 256 + threadIdx.x) * 4;
  int stride = gridDim.x * 256 * 4;
  for (; i < n; i += stride) {
    float4 v = *reinterpret_cast<const float4*>(src + i);
    ushort4 o;
    o.x = f2b(v.x); o.y = f2b(v.y); o.z = f2b(v.z); o.w = f2b(v.w);
    *reinterpret_cast<ushort4*>(dst + i) = o;
  }
}

// GEMM: A [Mrows x Kd] bf16 row-major, Bm [Kd x N] bf16 row-major.
// EPI=0: QKV epilogue: Q scaled [bh][t][d]; K swizzled [bh][t][d^]; V transposed+swizzled [bh][d][t^].
// EPI=1: fp32 out + bias.
template <int EPI>
__global__ __launch_bounds__(256) void gemm_kernel(
    const ushort* __restrict__ A, const ushort* __restrict__ Bm,
    const float* __restrict__ bias, int N, int Kd,
    ushort* __restrict__ qo, ushort* __restrict__ ko, ushort* __restrict__ vo,
    float* __restrict__ fo) {
  constexpr int AS = 48, BS = 48;
  __shared__ ushort As[64 * AS];
  __shared__ ushort Bs[64 * BS];
  const int tid = threadIdx.x;
  const int lane = tid & 63;
  const int w = tid >> 6;
  const int c = lane & 15, g = lane >> 4;
  const int wm = w >> 1, wn = w & 1;
  const int m0 = blockIdx.y * 64, n0 = blockIdx.x * 64;

  f32x4 acc[2][2] = {};

  const int arow = tid >> 2, acol = (tid & 3) * 8;
  const int brow = tid >> 3, bcol = (tid & 7) * 8;

  for (int k0 = 0; k0 < Kd; k0 += 32) {
    __syncthreads();
    bf16x8 va = *reinterpret_cast<const bf16x8*>(A + (size_t)(m0 + arow) * Kd + k0 + acol);
    *reinterpret_cast<bf16x8*>(&As[arow * AS + acol]) = va;
    bf16x8 vb = *reinterpret_cast<const bf16x8*>(Bm + (size_t)(k0 + brow) * N + n0 + bcol);
#pragma unroll
    for (int i = 0; i < 8; i++) Bs[(bcol + i) * BS + brow] = (ushort)vb[i];
    __syncthreads();

    bf16x8 af[2], bfr[2];
#pragma unroll
    for (int mi = 0; mi < 2; mi++)
      af[mi] = *reinterpret_cast<const bf16x8*>(&As[(wm * 32 + mi * 16 + c) * AS + g * 8]);
#pragma unroll
    for (int ni = 0; ni < 2; ni++)
      bfr[ni] = *reinterpret_cast<const bf16x8*>(&Bs[(wn * 32 + ni * 16 + c) * BS + g * 8]);
#pragma unroll
    for (int mi = 0; mi < 2; mi++)
#pragma unroll
      for (int ni = 0; ni < 2; ni++)
        acc[mi][ni] = __builtin_amdgcn_mfma_f32_16x16x32_bf16(af[mi], bfr[ni], acc[mi][ni], 0, 0, 0);
  }

  if constexpr (EPI == 0) {
    if (n0 >= 1536) {
      // V tile: bias, transpose via LDS, store V^T swizzled: [bh][d][t ^ ((d&7)*8) within 64-blk]
      __shared__ ushort TPV[64 * 68];
      const int hh = (n0 - 1536) >> 6;
      const int bb = m0 >> 12;
      const int t0 = m0 & (T - 1);
#pragma unroll
      for (int mi = 0; mi < 2; mi++)
#pragma unroll
        for (int ni = 0; ni < 2; ni++) {
          const int dn = wn * 32 + ni * 16 + c;
          const float bv = bias[n0 + dn];
#pragma unroll
          for (int r = 0; r < 4; r++) {
            const int tl = wm * 32 + mi * 16 + g * 4 + r;
            TPV[dn * 68 + tl] = f2b(acc[mi][ni][r] + bv);
          }
        }
      __syncthreads();
      const int d = tid >> 2;
#pragma unroll
      for (int k2 = 0; k2 < 2; k2++) {
        const int x8 = (tid & 3) * 2 + k2;
        bf16x8 vv = *reinterpret_cast<const bf16x8*>(&TPV[d * 68 + x8 * 8]);
        *reinterpret_cast<bf16x8*>(
            vo + (size_t)((bb * H + hh) * 64 + d) * T + t0 + ((x8 ^ (d & 7)) * 8)) = vv;
      }
    } else {
#pragma unroll
      for (int mi = 0; mi < 2; mi++)
#pragma unroll
        for (int ni = 0; ni < 2; ni++) {
          const int n = n0 + wn * 32 + ni * 16 + c;
          const float bv = bias[n];
#pragma unroll
          for (int r = 0; r < 4; r++) {
            const int m = m0 + wm * 32 + mi * 16 + g * 4 + r;
            const float val = acc[mi][ni][r] + bv;
            const int part = (n >= 768) ? 1 : 0;
            const int ci = n - part * 768;
            const int hh = ci >> 6, dd = ci & 63;
            const int bb = m >> 12, t = m & (T - 1);
            if (part == 0) {
              qo[((size_t)(bb * H + hh) * T + t) * HD + dd] = f2b(val * QSCALE);
            } else {
              ko[((size_t)(bb * H + hh) * T + t) * HD + (dd ^ ((t & 7) << 3))] = f2b(val);
            }
          }
        }
    }
  } else {
#pragma unroll
    for (int mi = 0; mi < 2; mi++)
#pragma unroll
      for (int ni = 0; ni < 2; ni++) {
        const int n = n0 + wn * 32 + ni * 16 + c;
        const float bv = bias[n];
#pragma unroll
        for (int r = 0; r < 4; r++) {
          const int m = m0 + wm * 32 + mi * 16 + g * 4 + r;
          fo[(size_t)m * N + n] = acc[mi][ni][r] + bv;
        }
      }
  }
}

// Flash attention v4: 32x32x16 MFMA, swapped QK^T (S^T), O^T accumulation.
// 1536 blocks (= 24 bh x 64 q-tiles of 64 rows), 128 thr = 2 waves x 32 q-rows.
// All blocks co-resident (16.4KB LDS, 6 blocks/CU); bid->(bh,qt) mapping makes
// every stride-256 residue class sum to exactly 195 kv-tiles (per-CU balance).
__global__ __launch_bounds__(128, 3) void attn_kernel(
    const ushort* __restrict__ Qg, const ushort* __restrict__ Kg,
    const ushort* __restrict__ Vtg, ushort* __restrict__ Yg) {
  __shared__ ushort smem[8192];       // Ks [64*64] | Vs [64*64]; Yt unions at epilogue
  ushort* Ks = smem;
  ushort* Vs = smem + 4096;

  const int tid = threadIdx.x;
  const int lane = tid & 63;
  const int w = tid >> 6;             // 0..1
  const int l31 = lane & 31;
  const int hi = lane >> 5;

  // balanced bid -> (bh, qt): class r = bid&255 gets qt = {a,63-a,a,63-a,a,63-a}
  const int bid = blockIdx.x;
  const int r = bid & 255, kk = bid >> 8;
  const int bh = (kk >> 1) * 8 + (r & 7);
  const int a = r >> 3;
  const int qt = (kk & 1) ? (63 - a) : a;

  const int bb = bh / H, h = bh % H;
  const int q0 = qt * 64;
  const int q0w = q0 + w * 32;
  const int qc = q0w + l31;           // this lane's q row (softmax state col)

  const ushort* Qp = Qg + (size_t)bh * T * HD;
  const char* Kbp = (const char*)(Kg + (size_t)bh * T * HD);
  const char* Vbp = (const char*)(Vtg + (size_t)bh * HD * T);

  // Q B-fragments: B[k=ks*16+hi*8+j][n=q=l31]
  bf16x8 qf[4];
#pragma unroll
  for (int ks = 0; ks < 4; ks++)
    qf[ks] = *reinterpret_cast<const bf16x8*>(Qp + (size_t)qc * HD + ks * 16 + hi * 8);

  float mrun = -1e30f, lrun = 0.f;
  f32x16 o16[2];  // O^T accum: d = dt*32 + crow(r,hi), q = l31
  o16[0] = zero16();
  o16[1] = zero16();

  const int vrow = lane >> 3;
  const int vcol16 = lane & 7;

  for (int kt = 0; kt <= qt; kt++) {
    const int kv0 = kt * 64;
    __syncthreads();
#pragma unroll
    for (int c2 = 0; c2 < 4; c2++) {
      const int chk = w * 4 + c2;
      gload16(Kbp + (size_t)kv0 * 128 + chk * 1024 + lane * 16, (char*)Ks + chk * 1024);
      gload16(Vbp + ((size_t)(chk * 8 + vrow) * T + kv0) * 2 + vcol16 * 16,
              (char*)Vs + chk * 1024);
    }
    __syncthreads();

    const bool have[2] = {kv0 <= q0w + 31, kv0 + 32 <= q0w + 31};
    const bool needm[2] = {kv0 + 31 > q0w, kv0 + 63 > q0w};

    // S^T = K x Q^T : per sub, lane holds S^T[kv = kv0+sub*32+crow(r,hi)][q=l31]
    f32x16 s2[2];
    __builtin_amdgcn_s_setprio(1);
#pragma unroll
    for (int sub = 0; sub < 2; sub++) {
      if (!have[sub]) continue;
      f32x16 sacc = zero16();
      const int row = sub * 32 + l31;
      const int sw = (row & 7) << 3;
#pragma unroll
      for (int ks = 0; ks < 4; ks++) {
        bf16x8 kf = *reinterpret_cast<const bf16x8*>(&Ks[row * 64 + ((ks * 16 + hi * 8) ^ sw)]);
        sacc = __builtin_amdgcn_mfma_f32_32x32x16_bf16(kf, qf[ks], sacc, 0, 0, 0);
      }
      if (needm[sub]) {
#pragma unroll
        for (int r2 = 0; r2 < 16; r2++) {
          const int kv = kv0 + sub * 32 + (r2 & 3) + ((r2 >> 2) << 3) + (hi << 2);
          if (kv > qc) sacc[r2] = -1e30f;
        }
      }
      s2[sub] = sacc;
    }
    __builtin_amdgcn_s_setprio(0);

    // online softmax: per-lane (q = l31); one cross shuffle (lane^32 holds other kv half)
    float pm = -1e30f;
#pragma unroll
    for (int sub = 0; sub < 2; sub++) {
      if (!have[sub]) continue;
#pragma unroll
      for (int r2 = 0; r2 < 16; r2++) pm = fmaxf(pm, s2[sub][r2]);
    }
    pm = fmaxf(pm, __shfl_xor(pm, 32));
    // defer-max (THR=8): only rescale when the tile max meaningfully exceeds ref
    if (__any(pm > mrun + 8.f)) {
      const float mnew = fmaxf(mrun, pm);
      const float corr = exp2f(mrun - mnew);
      lrun *= corr;
#pragma unroll
      for (int dt = 0; dt < 2; dt++)
#pragma unroll
        for (int r2 = 0; r2 < 16; r2++) o16[dt][r2] *= corr;
      mrun = mnew;
    }
    float sum = 0.f;
#pragma unroll
    for (int sub = 0; sub < 2; sub++) {
      if (!have[sub]) continue;
#pragma unroll
      for (int r2 = 0; r2 < 16; r2++) {
        const float p = exp2f(s2[sub][r2] - mrun);
        s2[sub][r2] = p;
        sum += p;
      }
    }
    sum += __shfl_xor(sum, 32);
    lrun += sum;

    // P^T B-frag in-register (cvt_pk + permlane32_swap), then O^T += V^T x P^T
#pragma unroll
    for (int sub = 0; sub < 2; sub++) {
      if (!have[sub]) continue;
#pragma unroll
      for (int ks2 = 0; ks2 < 2; ks2++) {
        const int r0 = ks2 * 8;
        int a0, a1, b0, b1;
        asm("v_cvt_pk_bf16_f32 %0, %1, %2" : "=v"(a0) : "v"(s2[sub][r0 + 0]), "v"(s2[sub][r0 + 1]));
        asm("v_cvt_pk_bf16_f32 %0, %1, %2" : "=v"(a1) : "v"(s2[sub][r0 + 2]), "v"(s2[sub][r0 + 3]));
        asm("v_cvt_pk_bf16_f32 %0, %1, %2" : "=v"(b0) : "v"(s2[sub][r0 + 4]), "v"(s2[sub][r0 + 5]));
        asm("v_cvt_pk_bf16_f32 %0, %1, %2" : "=v"(b1) : "v"(s2[sub][r0 + 6]), "v"(s2[sub][r0 + 7]));
        asm("v_permlane32_swap_b32 %0, %1" : "+v"(a0), "+v"(b0));
        asm("v_permlane32_swap_b32 %0, %1" : "+v"(a1), "+v"(b1));
        const i32x4 pi = {a0, a1, b0, b1};
        const bf16x8 pf = __builtin_bit_cast(bf16x8, pi);
        __builtin_amdgcn_s_setprio(1);
#pragma unroll
        for (int dt = 0; dt < 2; dt++) {
          const int drow = dt * 32 + l31;
          const int sw = (drow & 7) << 3;
          bf16x8 vf = *reinterpret_cast<const bf16x8*>(
              &Vs[drow * 64 + ((sub * 32 + ks2 * 16 + hi * 8) ^ sw)]);
          o16[dt] = __builtin_amdgcn_mfma_f32_32x32x16_bf16(vf, pf, o16[dt], 0, 0, 0);
        }
        __builtin_amdgcn_s_setprio(0);
      }
    }
  }  // kt

  // epilogue: O^T -> LDS transpose (smem reused) -> coalesced Y write
  ushort* Yt = smem;  // [64][68]
  __syncthreads();
  const float linv = 1.0f / lrun;
#pragma unroll
  for (int dt = 0; dt < 2; dt++)
#pragma unroll
    for (int r2 = 0; r2 < 16; r2++) {
      const int d = dt * 32 + (r2 & 3) + ((r2 >> 2) << 3) + (hi << 2);
      Yt[(w * 32 + l31) * 68 + d] = f2b(o16[dt][r2] * linv);
    }
  __syncthreads();
  {
    const int row = tid >> 1;       // 0..63
    const int half = tid & 1;
#pragma unroll
    for (int seg = 0; seg < 4; seg++) {
      bf16x8 vv = *reinterpret_cast<const bf16x8*>(&Yt[row * 68 + half * 32 + seg * 8]);
      *reinterpret_cast<bf16x8*>(
          Yg + ((size_t)(bb * T + q0 + row)) * C + h * 64 + half * 32 + seg * 8) = vv;
    }
  }
}

extern "C" void kernel_launch(void* const* d_in, const int* in_sizes, int n_in,
                              void* d_out, int out_size, void* d_ws, size_t ws_size,
                              hipStream_t stream) {
  const float* x = (const float*)d_in[0];
  const float* Wa = (const float*)d_in[1];
  const float* ba = (const float*)d_in[2];
  const float* Wp = (const float*)d_in[3];
  const float* bp = (const float*)d_in[4];
  float* out = (float*)d_out;

  char* ws = (char*)d_ws;
  size_t off = 0;
  auto carve = [&](size_t bytes) {
    void* p = ws + off;
    off += (bytes + 255) & ~(size_t)255;
    return p;
  };
  ushort* xb  = (ushort*)carve((size_t)M * C * 2);
  ushort* Wab = (ushort*)carve((size_t)C * N3 * 2);
  ushort* Wpb = (ushort*)carve((size_t)C * C * 2);
  ushort* Qb  = (ushort*)carve((size_t)BH * T * HD * 2);
  ushort* Kb  = (ushort*)carve((size_t)BH * T * HD * 2);
  ushort* Vtb = (ushort*)carve((size_t)BH * HD * T * 2);
  ushort* Yb  = (ushort*)carve((size_t)M * C * 2);

  cvt_kernel<<<2048, 256, 0, stream>>>(x, xb, M * C);
  cvt_kernel<<<1024, 256, 0, stream>>>(Wa, Wab, C * N3);
  cvt_kernel<<<576, 256, 0, stream>>>(Wp, Wpb, C * C);

  gemm_kernel<0><<<dim3(N3 / 64, M / 64), 256, 0, stream>>>(
      xb, Wab, ba, N3, C, Qb, Kb, Vtb, nullptr);

  attn_kernel<<<dim3(1536), 128, 0, stream>>>(Qb, Kb, Vtb, Yb);

  gemm_kernel<1><<<dim3(C / 64, M / 64), 256, 0, stream>>>(
      Yb, Wpb, bp, C, C, nullptr, nullptr, nullptr, out);
}

// Round 5
// 224.264 us; speedup vs baseline: 3.3993x; 1.4790x over previous
//
#include <hip/hip_runtime.h>
#include <hip/hip_bf16.h>

typedef __attribute__((ext_vector_type(8))) short bf16x8;
typedef __attribute__((ext_vector_type(4))) float f32x4;
typedef __attribute__((ext_vector_type(16))) float f32x16;
typedef __attribute__((ext_vector_type(4))) int i32x4;

#define DEVI __device__ __forceinline__

namespace {
constexpr int BATCH = 2;
constexpr int T = 4096;
constexpr int C = 768;
constexpr int H = 12;
constexpr int HD = 64;
constexpr int M = BATCH * T;     // 8192
constexpr int N3 = 3 * C;        // 2304
constexpr int BH = BATCH * H;    // 24
constexpr float QSCALE = 0.125f * 1.44269504088896f;  // 1/sqrt(64) * log2(e)
}  // namespace

DEVI ushort f2b(float f) {
  union { float f; unsigned u; } v; v.f = f;
  unsigned r = (v.u + 0x7FFFu + ((v.u >> 16) & 1u)) >> 16;
  return (ushort)r;
}

DEVI f32x16 zero16() {
  f32x16 z;
#pragma unroll
  for (int i = 0; i < 16; i++) z[i] = 0.f;
  return z;
}

// async 16B global->LDS. LDS dest is wave-uniform base; HW adds lane*16.
DEVI void gload16(const void* g, void* l) {
  __builtin_amdgcn_global_load_lds(
      (const __attribute__((address_space(1))) unsigned int*)g,
      (__attribute__((address_space(3))) unsigned int*)l, 16, 0, 0);
}

__global__ __launch_bounds__(256) void cvt_kernel(const float* __restrict__ src,
                                                  ushort* __restrict__ dst, int n) {
  int i = (blockIdx.x * 256 + threadIdx.x) * 4;
  int stride = gridDim.x * 256 * 4;
  for (; i < n; i += stride) {
    float4 v = *reinterpret_cast<const float4*>(src + i);
    ushort4 o;
    o.x = f2b(v.x); o.y = f2b(v.y); o.z = f2b(v.z); o.w = f2b(v.w);
    *reinterpret_cast<ushort4*>(dst + i) = o;
  }
}

// Transpose-convert: f32 W [K][N] -> bf16 W^T [N][K]. 64x64 tiles.
__global__ __launch_bounds__(256) void cvtT_kernel(const float* __restrict__ src,
                                                   ushort* __restrict__ dst,
                                                   int K, int N) {
  __shared__ ushort Lt[64 * 68];
  const int k0 = blockIdx.x * 64, n0 = blockIdx.y * 64;
  const int tid = threadIdx.x;
  const int rr = tid >> 4, c4 = (tid & 15) * 4;
#pragma unroll
  for (int it = 0; it < 4; it++) {
    const int r = it * 16 + rr;
    float4 v = *reinterpret_cast<const float4*>(src + (size_t)(k0 + r) * N + n0 + c4);
    Lt[(c4 + 0) * 68 + r] = f2b(v.x);
    Lt[(c4 + 1) * 68 + r] = f2b(v.y);
    Lt[(c4 + 2) * 68 + r] = f2b(v.z);
    Lt[(c4 + 3) * 68 + r] = f2b(v.w);
  }
  __syncthreads();
#pragma unroll
  for (int it = 0; it < 4; it++) {
    const int r = it * 16 + rr;
    *reinterpret_cast<ushort4*>(dst + (size_t)(n0 + r) * K + k0 + c4) =
        *reinterpret_cast<const ushort4*>(&Lt[r * 68 + c4]);
  }
}

// m97-style GEMM: A [Mrows x Kd] bf16 row-major, Bt = B^T [N x Kd] bf16 row-major.
// 32x32x16 MFMA, gload_lds staging with XOR-8 k-swizzle, BK=64, 256 thr = 4 waves.
// EPI=0: BM=128,BN=128, QKV epilogue (Q scaled; K d-swizzled; V transposed+t-swizzled).
// EPI=1: BM=64, BN=128, f32 out + bias.
template <int EPI>
__global__ __launch_bounds__(256, 3) void gemm_kernel(
    const ushort* __restrict__ A, const ushort* __restrict__ Bt,
    const float* __restrict__ bias, int N, int Kd,
    ushort* __restrict__ qo, ushort* __restrict__ ko, ushort* __restrict__ vo,
    float* __restrict__ fo) {
  constexpr int BM = (EPI == 0) ? 128 : 64;
  constexpr int BN = 128;
  constexpr int WN = (EPI == 0) ? 2 : 4;   // waves along n
  constexpr int WTN = BN / WN;             // 64 or 32
  constexpr int NT = WTN / 32;             // 2 or 1
  constexpr int CH_A = BM / 8;             // 1KB chunks in A tile
  constexpr int CH_B = BN / 8;
  constexpr int CPW = (CH_A + CH_B) / 4;
  constexpr int SMEM = (EPI == 0) ? (4 * 64 * 68) : ((BM + BN) * 64);
  __shared__ ushort smem[SMEM];
  ushort* As = smem;
  ushort* Bs = smem + BM * 64;

  const int tid = threadIdx.x;
  const int lane = tid & 63;
  const int w = tid >> 6;
  const int l31 = lane & 31;
  const int hi = lane >> 5;
  const int wm = w / WN, wn = w % WN;
  const int m0 = blockIdx.y * BM, n0 = blockIdx.x * BN;
  const int r8 = lane >> 3, c8 = lane & 7;
  const int csw = (c8 ^ r8) * 8;

  f32x16 acc[2][NT];
#pragma unroll
  for (int mt = 0; mt < 2; mt++)
#pragma unroll
    for (int nt = 0; nt < NT; nt++) acc[mt][nt] = zero16();

  for (int k0 = 0; k0 < Kd; k0 += 64) {
    __syncthreads();
#pragma unroll
    for (int ci = 0; ci < CPW; ci++) {
      const int chk = w * CPW + ci;
      if (chk < CH_A) {
        gload16(A + (size_t)(m0 + chk * 8 + r8) * Kd + k0 + csw, (char*)As + chk * 1024);
      } else {
        const int ch2 = chk - CH_A;
        gload16(Bt + (size_t)(n0 + ch2 * 8 + r8) * Kd + k0 + csw, (char*)Bs + ch2 * 1024);
      }
    }
    __syncthreads();
#pragma unroll
    for (int ks = 0; ks < 4; ks++) {
      bf16x8 af[2], bf[NT];
#pragma unroll
      for (int mt = 0; mt < 2; mt++) {
        const int rl = wm * 64 + mt * 32 + l31;
        af[mt] = *reinterpret_cast<const bf16x8*>(
            &As[rl * 64 + ((ks * 16 + hi * 8) ^ ((rl & 7) * 8))]);
      }
#pragma unroll
      for (int nt = 0; nt < NT; nt++) {
        const int nl = wn * WTN + nt * 32 + l31;
        bf[nt] = *reinterpret_cast<const bf16x8*>(
            &Bs[nl * 64 + ((ks * 16 + hi * 8) ^ ((nl & 7) * 8))]);
      }
#pragma unroll
      for (int mt = 0; mt < 2; mt++)
#pragma unroll
        for (int nt = 0; nt < NT; nt++)
          acc[mt][nt] = __builtin_amdgcn_mfma_f32_32x32x16_bf16(af[mt], bf[nt], acc[mt][nt], 0, 0, 0);
    }
  }

  // C layout (verified): col = l31, row = (r&3) + 8*(r>>2) + 4*hi
  if constexpr (EPI == 0) {
    if (n0 >= 1536) {
      // V tile: bias, per-wave transpose via LDS, store V^T [bh][d][t^swz]
      __syncthreads();
      ushort* Vw = smem + w * 4352;  // [64 d][68]
      const float bv0 = bias[n0 + wn * 64 + l31];
      const float bv1 = bias[n0 + wn * 64 + 32 + l31];
#pragma unroll
      for (int mt = 0; mt < 2; mt++)
#pragma unroll
        for (int nt = 0; nt < 2; nt++) {
          const float bv = nt ? bv1 : bv0;
#pragma unroll
          for (int r = 0; r < 16; r++) {
            const int trow = mt * 32 + (r & 3) + ((r >> 2) << 3) + (hi << 2);
            Vw[(nt * 32 + l31) * 68 + trow] = f2b(acc[mt][nt][r] + bv);
          }
        }
      const int hh = (n0 - 1536) / 64 + wn;
      const int bb = m0 >> 12;
      const int t0 = (m0 & (T - 1)) + wm * 64;
      const size_t vbase = (size_t)((bb * H + hh) * 64 + lane) * T + t0;
#pragma unroll
      for (int x8 = 0; x8 < 8; x8++) {
        bf16x8 vv = *reinterpret_cast<const bf16x8*>(&Vw[lane * 68 + x8 * 8]);
        *reinterpret_cast<bf16x8*>(vo + vbase + ((x8 ^ (lane & 7)) * 8)) = vv;
      }
    } else {
#pragma unroll
      for (int mt = 0; mt < 2; mt++)
#pragma unroll
        for (int nt = 0; nt < 2; nt++) {
          const int n = n0 + wn * 64 + nt * 32 + l31;
          const float bv = bias[n];
          const int part = (n >= 768) ? 1 : 0;
          const int ci = n - part * 768;
          const int hh = ci >> 6, dd = ci & 63;
#pragma unroll
          for (int r = 0; r < 16; r++) {
            const int m = m0 + wm * 64 + mt * 32 + (r & 3) + ((r >> 2) << 3) + (hi << 2);
            const int bb = m >> 12, t = m & (T - 1);
            const float val = acc[mt][nt][r] + bv;
            if (part == 0) {
              qo[((size_t)(bb * H + hh) * T + t) * HD + dd] = f2b(val * QSCALE);
            } else {
              ko[((size_t)(bb * H + hh) * T + t) * HD + (dd ^ ((t & 7) << 3))] = f2b(val);
            }
          }
        }
    }
  } else {
#pragma unroll
    for (int mt = 0; mt < 2; mt++)
#pragma unroll
      for (int nt = 0; nt < NT; nt++) {
        const int n = n0 + wn * WTN + nt * 32 + l31;
        const float bv = bias[n];
#pragma unroll
        for (int r = 0; r < 16; r++) {
          const int m = m0 + wm * 64 + mt * 32 + (r & 3) + ((r >> 2) << 3) + (hi << 2);
          fo[(size_t)m * N + n] = acc[mt][nt][r] + bv;
        }
      }
  }
}

// Flash attention v5: paired q-tiles (uniform 65 kv-tiles/block), double-buffered
// LDS with counted vmcnt pipeline. 768 blocks x 128 thr (2 waves x 32 q).
__global__ __launch_bounds__(128, 2) void attn_kernel(
    const ushort* __restrict__ Qg, const ushort* __restrict__ Kg,
    const ushort* __restrict__ Vtg, ushort* __restrict__ Yg) {
  // smem: buf0{K,V} | buf1{K,V} | per-wave Yt [32][36]
  __shared__ ushort smem[16384 + 2 * 32 * 36];

  const int tid = threadIdx.x;
  const int lane = tid & 63;
  const int w = tid >> 6;
  const int l31 = lane & 31;
  const int hi = lane >> 5;
  const int r8 = lane >> 3, c8 = lane & 7;

  // bid -> (bh, a): XCD-grouped (3 heads per XCD), uniform work (65 tiles each)
  const int bid = blockIdx.x;
  const int xcd = bid & 7, idx = bid >> 3;
  const int bh = xcd * 3 + idx % 3;
  const int a = idx / 3;  // 0..31: passes qt=a then qt=63-a

  const int bb = bh / H, h = bh % H;
  const ushort* Qp = Qg + (size_t)bh * T * HD;
  const char* Kbp = (const char*)(Kg + (size_t)bh * T * HD);
  const char* Vbp = (const char*)(Vtg + (size_t)bh * HD * T);

  // Q B-fragments for both passes
  bf16x8 qfa[4], qfb[4], qcur[4];
  const int qr0 = a * 64 + w * 32 + l31;
  const int qr1 = (63 - a) * 64 + w * 32 + l31;
#pragma unroll
  for (int ks = 0; ks < 4; ks++) {
    qfa[ks] = *reinterpret_cast<const bf16x8*>(Qp + (size_t)qr0 * HD + ks * 16 + hi * 8);
    qfb[ks] = *reinterpret_cast<const bf16x8*>(Qp + (size_t)qr1 * HD + ks * 16 + hi * 8);
    qcur[ks] = qfa[ks];
  }

  int q0 = a * 64;
  int q0w = q0 + w * 32;
  int qc = q0w + l31;

  float mrun = -1e30f, lrun = 0.f;
  f32x16 o16[2];
  o16[0] = zero16();
  o16[1] = zero16();

  const int boundary = a + 1;       // first tile index of pass1
  const int nt_tot = 65;

  auto kv0_of = [&](int tt) { return (tt < boundary ? tt : tt - boundary) * 64; };

  auto issue_tile = [&](int tt) {
    const int kv0 = kv0_of(tt);
    ushort* kb = smem + (tt & 1) * 8192;
    ushort* vb = kb + 4096;
#pragma unroll
    for (int c2 = 0; c2 < 4; c2++) {
      const int chk = w * 4 + c2;
      gload16(Kbp + ((size_t)(kv0 + chk * 8 + r8) * 64 + c8 * 8) * 2, (char*)kb + chk * 1024);
      gload16(Vbp + ((size_t)(chk * 8 + r8) * T + kv0 + c8 * 8) * 2, (char*)vb + chk * 1024);
    }
  };

  auto epilogue = [&](int q0p, float lr) {
    ushort* Yt = smem + 16384 + w * 1152;  // [32 q][36]
    const float linv = 1.0f / lr;
#pragma unroll
    for (int dt = 0; dt < 2; dt++) {
#pragma unroll
      for (int r = 0; r < 16; r++) {
        const int d32 = (r & 3) + ((r >> 2) << 3) + (hi << 2);
        Yt[l31 * 36 + d32] = f2b(o16[dt][r] * linv);
      }
#pragma unroll
      for (int seg = 0; seg < 2; seg++) {
        bf16x8 vv = *reinterpret_cast<const bf16x8*>(&Yt[l31 * 36 + hi * 16 + seg * 8]);
        *reinterpret_cast<bf16x8*>(
            Yg + ((size_t)(bb * T + q0p + w * 32 + l31)) * C + h * 64 + dt * 32 + hi * 16 + seg * 8) = vv;
      }
    }
  };

  issue_tile(0);

  for (int tt = 0; tt < nt_tot; tt++) {
    if (tt + 1 < nt_tot) {
      issue_tile(tt + 1);
      asm volatile("s_waitcnt vmcnt(8)" ::: "memory");
    } else {
      asm volatile("s_waitcnt vmcnt(0)" ::: "memory");
    }
    __builtin_amdgcn_s_barrier();
    __builtin_amdgcn_sched_barrier(0);

    if (tt == boundary) {
      // flush pass0, reset state for pass1
      epilogue(q0, lrun);
      mrun = -1e30f; lrun = 0.f;
      o16[0] = zero16(); o16[1] = zero16();
#pragma unroll
      for (int ks = 0; ks < 4; ks++) qcur[ks] = qfb[ks];
      q0 = (63 - a) * 64;
      q0w = q0 + w * 32;
      qc = q0w + l31;
    }

    const int kv0 = kv0_of(tt);
    const ushort* Ks = smem + (tt & 1) * 8192;
    const ushort* Vs = Ks + 4096;

    const bool have[2] = {kv0 <= q0w + 31, kv0 + 32 <= q0w + 31};
    const bool needm[2] = {kv0 + 31 > q0w, kv0 + 63 > q0w};

    // S^T = K x Q^T
    f32x16 s2[2];
    __builtin_amdgcn_s_setprio(1);
#pragma unroll
    for (int sub = 0; sub < 2; sub++) {
      if (!have[sub]) continue;
      f32x16 sacc = zero16();
      const int row = sub * 32 + l31;
      const int sw = (row & 7) << 3;
#pragma unroll
      for (int ks = 0; ks < 4; ks++) {
        bf16x8 kf = *reinterpret_cast<const bf16x8*>(&Ks[row * 64 + ((ks * 16 + hi * 8) ^ sw)]);
        sacc = __builtin_amdgcn_mfma_f32_32x32x16_bf16(kf, qcur[ks], sacc, 0, 0, 0);
      }
      if (needm[sub]) {
#pragma unroll
        for (int r2 = 0; r2 < 16; r2++) {
          const int kv = kv0 + sub * 32 + (r2 & 3) + ((r2 >> 2) << 3) + (hi << 2);
          if (kv > qc) sacc[r2] = -1e30f;
        }
      }
      s2[sub] = sacc;
    }
    __builtin_amdgcn_s_setprio(0);

    // online softmax (per-lane q = l31), defer-max THR=8
    float pm = -1e30f;
#pragma unroll
    for (int sub = 0; sub < 2; sub++) {
      if (!have[sub]) continue;
#pragma unroll
      for (int r2 = 0; r2 < 16; r2++) pm = fmaxf(pm, s2[sub][r2]);
    }
    pm = fmaxf(pm, __shfl_xor(pm, 32));
    if (__any(pm > mrun + 8.f)) {
      const float mnew = fmaxf(mrun, pm);
      const float corr = exp2f(mrun - mnew);
      lrun *= corr;
#pragma unroll
      for (int dt = 0; dt < 2; dt++)
#pragma unroll
        for (int r2 = 0; r2 < 16; r2++) o16[dt][r2] *= corr;
      mrun = mnew;
    }
    float sum = 0.f;
#pragma unroll
    for (int sub = 0; sub < 2; sub++) {
      if (!have[sub]) continue;
#pragma unroll
      for (int r2 = 0; r2 < 16; r2++) {
        const float p = exp2f(s2[sub][r2] - mrun);
        s2[sub][r2] = p;
        sum += p;
      }
    }
    sum += __shfl_xor(sum, 32);
    lrun += sum;

    // P^T B-frag in-register, then O^T += V^T x P^T
#pragma unroll
    for (int sub = 0; sub < 2; sub++) {
      if (!have[sub]) continue;
#pragma unroll
      for (int ks2 = 0; ks2 < 2; ks2++) {
        const int r0 = ks2 * 8;
        int a0, a1, b0, b1;
        asm("v_cvt_pk_bf16_f32 %0, %1, %2" : "=v"(a0) : "v"(s2[sub][r0 + 0]), "v"(s2[sub][r0 + 1]));
        asm("v_cvt_pk_bf16_f32 %0, %1, %2" : "=v"(a1) : "v"(s2[sub][r0 + 2]), "v"(s2[sub][r0 + 3]));
        asm("v_cvt_pk_bf16_f32 %0, %1, %2" : "=v"(b0) : "v"(s2[sub][r0 + 4]), "v"(s2[sub][r0 + 5]));
        asm("v_cvt_pk_bf16_f32 %0, %1, %2" : "=v"(b1) : "v"(s2[sub][r0 + 6]), "v"(s2[sub][r0 + 7]));
        asm("v_permlane32_swap_b32 %0, %1" : "+v"(a0), "+v"(b0));
        asm("v_permlane32_swap_b32 %0, %1" : "+v"(a1), "+v"(b1));
        const i32x4 pi = {a0, a1, b0, b1};
        const bf16x8 pf = __builtin_bit_cast(bf16x8, pi);
        __builtin_amdgcn_s_setprio(1);
#pragma unroll
        for (int dt = 0; dt < 2; dt++) {
          const int drow = dt * 32 + l31;
          const int sw = (drow & 7) << 3;
          bf16x8 vf = *reinterpret_cast<const bf16x8*>(
              &Vs[drow * 64 + ((sub * 32 + ks2 * 16 + hi * 8) ^ sw)]);
          o16[dt] = __builtin_amdgcn_mfma_f32_32x32x16_bf16(vf, pf, o16[dt], 0, 0, 0);
        }
        __builtin_amdgcn_s_setprio(0);
      }
    }

    asm volatile("s_waitcnt lgkmcnt(0)" ::: "memory");
    __builtin_amdgcn_s_barrier();
  }  // tt

  epilogue(q0, lrun);
}

extern "C" void kernel_launch(void* const* d_in, const int* in_sizes, int n_in,
                              void* d_out, int out_size, void* d_ws, size_t ws_size,
                              hipStream_t stream) {
  const float* x = (const float*)d_in[0];
  const float* Wa = (const float*)d_in[1];
  const float* ba = (const float*)d_in[2];
  const float* Wp = (const float*)d_in[3];
  const float* bp = (const float*)d_in[4];
  float* out = (float*)d_out;

  char* ws = (char*)d_ws;
  size_t off = 0;
  auto carve = [&](size_t bytes) {
    void* p = ws + off;
    off += (bytes + 255) & ~(size_t)255;
    return p;
  };
  ushort* xb   = (ushort*)carve((size_t)M * C * 2);
  ushort* WaT  = (ushort*)carve((size_t)N3 * C * 2);
  ushort* WpT  = (ushort*)carve((size_t)C * C * 2);
  ushort* Qb   = (ushort*)carve((size_t)BH * T * HD * 2);
  ushort* Kb   = (ushort*)carve((size_t)BH * T * HD * 2);
  ushort* Vtb  = (ushort*)carve((size_t)BH * HD * T * 2);
  ushort* Yb   = (ushort*)carve((size_t)M * C * 2);

  cvt_kernel<<<2048, 256, 0, stream>>>(x, xb, M * C);
  cvtT_kernel<<<dim3(C / 64, N3 / 64), 256, 0, stream>>>(Wa, WaT, C, N3);
  cvtT_kernel<<<dim3(C / 64, C / 64), 256, 0, stream>>>(Wp, WpT, C, C);

  gemm_kernel<0><<<dim3(N3 / 128, M / 128), 256, 0, stream>>>(
      xb, WaT, ba, N3, C, Qb, Kb, Vtb, nullptr);

  attn_kernel<<<dim3(768), 128, 0, stream>>>(Qb, Kb, Vtb, Yb);

  gemm_kernel<1><<<dim3(C / 128, M / 64), 256, 0, stream>>>(
      Yb, WpT, bp, C, C, nullptr, nullptr, nullptr, out);
}